// Round 5
// baseline (851.270 us; speedup 1.0000x reference)
//
#include <hip/hip_runtime.h>

#define NN 30000
#define NE 120000
#define NG 938   // ceil(NN/32)
#define TPB 256

__global__ void k_zero(int* __restrict__ cnt) {
  int n = blockIdx.x * TPB + threadIdx.x;
  if (n < NN) cnt[n] = 0;
}

// kc[e] = {relu(ea@k_w1+k_b1) (8), 1.0, 0.0}; cnt[dst]++
__global__ void k_prep(const float* __restrict__ ea, const float* __restrict__ w1,
                       const float* __restrict__ b1, const int* __restrict__ dst,
                       float* __restrict__ kc, int* __restrict__ cnt) {
  int e = blockIdx.x * TPB + threadIdx.x;
  if (e >= NE) return;
  float a[6];
#pragma unroll
  for (int i = 0; i < 6; i++) a[i] = ea[e * 6 + i];
#pragma unroll
  for (int k = 0; k < 8; k++) {
    float s = b1[k];
#pragma unroll
    for (int i = 0; i < 6; i++) s = fmaf(a[i], w1[i * 8 + k], s);
    kc[e * 10 + k] = fmaxf(s, 0.f);
  }
  kc[e * 10 + 8] = 1.f;
  kc[e * 10 + 9] = 0.f;
  atomicAdd(&cnt[dst[e]], 1);
}

// single-block prefix scan: rowstart/wpos = exclusive prefix of cnt; icnt = 1/max(cnt,1)
__global__ void k_scan(const int* __restrict__ cnt, int* __restrict__ rowstart,
                       int* __restrict__ wpos, float* __restrict__ icnt) {
  __shared__ int S[1024];
  int t = threadIdx.x;
  int base = t * 30;
  int s = 0;
  for (int j = 0; j < 30; j++) {
    int n = base + j;
    if (n < NN) s += cnt[n];
  }
  S[t] = s;
  __syncthreads();
  for (int off = 1; off < 1024; off <<= 1) {
    int v = S[t] + ((t >= off) ? S[t - off] : 0);
    __syncthreads();
    S[t] = v;
    __syncthreads();
  }
  int pref = (t > 0) ? S[t - 1] : 0;
  for (int j = 0; j < 30; j++) {
    int n = base + j;
    if (n < NN) {
      int c = cnt[n];
      rowstart[n] = pref;
      wpos[n] = pref;
      icnt[n] = 1.f / (float)max(c, 1);
      pref += c;
    }
  }
}

__global__ void k_scatter(const int* __restrict__ dst, int* __restrict__ wpos,
                          int* __restrict__ order) {
  int e = blockIdx.x * TPB + threadIdx.x;
  if (e >= NE) return;
  int pos = atomicAdd(&wpos[dst[e]], 1);
  order[pos] = e;
}

__device__ __forceinline__ unsigned short f2b(float f) {
  unsigned u = __float_as_uint(f);
  return (unsigned short)((u + 0x7fff + ((u >> 16) & 1)) >> 16);  // RNE
}

// 32-node transform (R3-verified math): Pb[n][o][k-pair] packed bf16, Pr[n][o] = root term
__device__ __forceinline__ void transform32(const float* hL, const float* Wl,
                                            unsigned int* Pb, float* Pr,
                                            int base, int tid) {
  int g = tid >> 5, o = tid & 31, sw = (o & 7) << 2;
#pragma unroll
  for (int pp = 0; pp < 2; pp++) {
    int ln0 = pp * 16 + g, ln1 = ln0 + 8;
    float4 hv0[8], hv1[8];
#pragma unroll
    for (int c = 0; c < 8; c++) {
      hv0[c] = *(const float4*)&hL[ln0 * 32 + c * 4];
      hv1[c] = *(const float4*)&hL[ln1 * 32 + c * 4];
    }
    int n0 = base + ln0, n1 = base + ln1;
    float a0[10], a1[10];
#pragma unroll
    for (int k = 0; k < 10; k++) {
      float x0 = 0.f, x1 = 0.f;
#pragma unroll
      for (int c = 0; c < 8; c++) {
        float4 w = *(const float4*)&Wl[k * 1024 + o * 32 + ((c << 2) ^ sw)];
        x0 = fmaf(hv0[c].x, w.x, x0); x1 = fmaf(hv1[c].x, w.x, x1);
        x0 = fmaf(hv0[c].y, w.y, x0); x1 = fmaf(hv1[c].y, w.y, x1);
        x0 = fmaf(hv0[c].z, w.z, x0); x1 = fmaf(hv1[c].z, w.z, x1);
        x0 = fmaf(hv0[c].w, w.w, x0); x1 = fmaf(hv1[c].w, w.w, x1);
      }
      a0[k] = x0; a1[k] = x1;
    }
    if (n0 < NN) {
      unsigned int* q = Pb + (size_t)(n0 * 32 + o) * 5;
      q[0] = f2b(a0[0]) | ((unsigned)f2b(a0[1]) << 16);
      q[1] = f2b(a0[2]) | ((unsigned)f2b(a0[3]) << 16);
      q[2] = f2b(a0[4]) | ((unsigned)f2b(a0[5]) << 16);
      q[3] = f2b(a0[6]) | ((unsigned)f2b(a0[7]) << 16);
      q[4] = (unsigned)f2b(a0[8]);
      Pr[n0 * 32 + o] = a0[9];
    }
    if (n1 < NN) {
      unsigned int* q = Pb + (size_t)(n1 * 32 + o) * 5;
      q[0] = f2b(a1[0]) | ((unsigned)f2b(a1[1]) << 16);
      q[1] = f2b(a1[2]) | ((unsigned)f2b(a1[3]) << 16);
      q[2] = f2b(a1[4]) | ((unsigned)f2b(a1[5]) << 16);
      q[3] = f2b(a1[6]) | ((unsigned)f2b(a1[7]) << 16);
      q[4] = (unsigned)f2b(a1[8]);
      Pr[n1 * 32 + o] = a1[9];
    }
  }
}

// MODE 0: h0 = fc1(x), transform -> Pbo/Pro
// MODE 1: CSR-aggregate from Pbi, h = relu(agg*icnt + Pri + cbias), transform -> Pbo/Pro
// MODE 2: aggregate, h, out = h @ fc2w + fc2b
template <int MODE>
__global__ __launch_bounds__(TPB, 2) void k_layer(
    const float* __restrict__ x, const float* __restrict__ fc1w,
    const float* __restrict__ fc1b, const float* __restrict__ kw2,
    const float* __restrict__ kb2, const float* __restrict__ root,
    const float* __restrict__ cbias, const float* __restrict__ fc2w,
    const float* __restrict__ fc2b, const float* __restrict__ kc,
    const int* __restrict__ src, const int* __restrict__ rowstart,
    const int* __restrict__ cnt, const float* __restrict__ icnt,
    const int* __restrict__ order, const unsigned int* __restrict__ Pbi,
    const float* __restrict__ Pri, unsigned int* __restrict__ Pbo,
    float* __restrict__ Pro, float* __restrict__ out) {
  __shared__ float Wl[10 * 1024];
  __shared__ float hL[1024];
  int tid = threadIdx.x;
  int base = blockIdx.x * 32;
  if (MODE != 2) {
    for (int f = tid; f < 10 * 1024; f += TPB) {
      int k = f >> 10, rem = f & 1023, i = rem >> 5, o = rem & 31;
      float v;
      if (f < 8192) v = kw2[f];
      else if (f < 9216) v = kb2[f - 8192];
      else v = root[f - 9216];
      Wl[(k * 1024 + o * 32 + i) ^ ((o & 7) << 2)] = v;
    }
  }
  int g = tid >> 5, o = tid & 31;
  if (MODE == 0) {
    for (int e2 = tid; e2 < 1024; e2 += TPB) {
      int ln = e2 >> 5, oo = e2 & 31, n = base + ln;
      hL[e2] = (n < NN) ? fmaf(x[n], fc1w[oo], fc1b[oo]) : 0.f;
    }
  } else {
#pragma unroll
    for (int q = 0; q < 4; q++) {
      int ln = q * 8 + g;
      int n = base + ln;
      float acc = 0.f;
      int rs = 0, re = 0;
      if (n < NN) { rs = rowstart[n]; re = rs + cnt[n]; }
      for (int j = rs; j < re; j++) {
        int e = order[j];
        int s = src[e];
        float ck = (o < 9) ? kc[e * 10 + o] : 0.f;
        const unsigned int* gp = Pbi + (size_t)s * 160 + o * 5;
        unsigned int u0 = gp[0], u1 = gp[1], u2 = gp[2], u3 = gp[3], u4 = gp[4];
        acc = fmaf(__shfl(ck, 0, 32), __uint_as_float(u0 << 16), acc);
        acc = fmaf(__shfl(ck, 1, 32), __uint_as_float(u0 & 0xffff0000u), acc);
        acc = fmaf(__shfl(ck, 2, 32), __uint_as_float(u1 << 16), acc);
        acc = fmaf(__shfl(ck, 3, 32), __uint_as_float(u1 & 0xffff0000u), acc);
        acc = fmaf(__shfl(ck, 4, 32), __uint_as_float(u2 << 16), acc);
        acc = fmaf(__shfl(ck, 5, 32), __uint_as_float(u2 & 0xffff0000u), acc);
        acc = fmaf(__shfl(ck, 6, 32), __uint_as_float(u3 << 16), acc);
        acc = fmaf(__shfl(ck, 7, 32), __uint_as_float(u3 & 0xffff0000u), acc);
        acc = fmaf(__shfl(ck, 8, 32), __uint_as_float(u4 << 16), acc);
      }
      if (n < NN) {
        float h = fmaxf(fmaf(acc, icnt[n], Pri[n * 32 + o] + cbias[o]), 0.f);
        if (MODE == 2) {
          float s2 = h * fc2w[o];
#pragma unroll
          for (int d2 = 16; d2; d2 >>= 1) s2 += __shfl_xor(s2, d2, 32);
          if (o == 0) out[n] = s2 + fc2b[0];
        } else {
          hL[ln * 32 + o] = h;
        }
      } else if (MODE == 1) {
        hL[ln * 32 + o] = 0.f;
      }
    }
  }
  if (MODE != 2) {
    __syncthreads();
    transform32(hL, Wl, Pbo, Pro, base, tid);
  }
}

extern "C" void kernel_launch(void* const* d_in, const int* in_sizes, int n_in,
                              void* d_out, int out_size, void* d_ws, size_t ws_size,
                              hipStream_t stream) {
  const float* x     = (const float*)d_in[0];
  const int*   ei    = (const int*)d_in[1];
  const float* ea    = (const float*)d_in[2];
  const float* fc1w  = (const float*)d_in[3];
  const float* fc1b  = (const float*)d_in[4];
  const float* kw1   = (const float*)d_in[5];
  const float* kb1   = (const float*)d_in[6];
  const float* kw2   = (const float*)d_in[7];
  const float* kb2   = (const float*)d_in[8];
  const float* root  = (const float*)d_in[9];
  const float* cbias = (const float*)d_in[10];
  const float* fc2w  = (const float*)d_in[11];
  const float* fc2b  = (const float*)d_in[12];
  float* out = (float*)d_out;
  const int* srcp = ei;
  const int* dstp = ei + NE;

  float* ws = (float*)d_ws;
  float* kc       = ws;                        // NE*10
  float* icnt     = kc + NE * 10;              // NN
  float* Pr0      = icnt + NN;                 // NN*32
  float* Pr1      = Pr0 + NN * 32;             // NN*32
  int*   cnt      = (int*)(Pr1 + NN * 32);     // NN
  int*   rowstart = cnt + NN;                  // NN
  int*   wpos     = rowstart + NN;             // NN
  int*   order    = wpos + NN;                 // NE
  unsigned int* Pb0 = (unsigned int*)(order + NE);  // NN*160
  unsigned int* Pb1 = Pb0 + (size_t)NN * 160;       // NN*160

  k_zero<<<(NN + TPB - 1) / TPB, TPB, 0, stream>>>(cnt);
  k_prep<<<(NE + TPB - 1) / TPB, TPB, 0, stream>>>(ea, kw1, kb1, dstp, kc, cnt);
  k_scan<<<1, 1024, 0, stream>>>(cnt, rowstart, wpos, icnt);
  k_scatter<<<(NE + TPB - 1) / TPB, TPB, 0, stream>>>(dstp, wpos, order);

  k_layer<0><<<NG, TPB, 0, stream>>>(x, fc1w, fc1b, kw2, kb2, root, cbias, fc2w,
                                     fc2b, kc, srcp, rowstart, cnt, icnt, order,
                                     Pb0, Pr0, Pb0, Pr0, out);
  k_layer<1><<<NG, TPB, 0, stream>>>(x, fc1w, fc1b, kw2, kb2, root, cbias, fc2w,
                                     fc2b, kc, srcp, rowstart, cnt, icnt, order,
                                     Pb0, Pr0, Pb1, Pr1, out);
  k_layer<1><<<NG, TPB, 0, stream>>>(x, fc1w, fc1b, kw2, kb2, root, cbias, fc2w,
                                     fc2b, kc, srcp, rowstart, cnt, icnt, order,
                                     Pb1, Pr1, Pb0, Pr0, out);
  k_layer<1><<<NG, TPB, 0, stream>>>(x, fc1w, fc1b, kw2, kb2, root, cbias, fc2w,
                                     fc2b, kc, srcp, rowstart, cnt, icnt, order,
                                     Pb0, Pr0, Pb1, Pr1, out);
  k_layer<2><<<NG, TPB, 0, stream>>>(x, fc1w, fc1b, kw2, kb2, root, cbias, fc2w,
                                     fc2b, kc, srcp, rowstart, cnt, icnt, order,
                                     Pb1, Pr1, Pb0, Pr0, out);
}